// Round 3
// baseline (550.424 us; speedup 1.0000x reference)
//
#include <hip/hip_runtime.h>
#include <hip/hip_bf16.h>

// Decoder: 2-layer LSTM (H=32) + MLP head (96), B=16384, 25 autoregressive steps.
// R2: passed at 517us, VALUBusy 43%, 1 wave/SIMD (159KB LDS -> 1 block/CU).
// R3: NTHR 512 (2 waves/SIMD), tile 4 gate-cols x 4 elems (gates of one unit
// thread-local), float4 activation writes, MLP o-major with register->global
// stores. Same dtype probe (inputs proved f32 in R2).

#define NTHR 512
#define ET   64      // batch elements per block
#define XS   68      // LDS row stride (floats): 16B-aligned, +4-bank row skew
#define PRED 25
#define BATCH 16384

typedef unsigned short u16;
typedef unsigned int   u32;

__device__ __forceinline__ float b2f(u16 u){ return __uint_as_float(((u32)u) << 16); }
__device__ __forceinline__ u16 f2b(float f){
  u32 i = __float_as_uint(f);
  i += 0x7FFFu + ((i >> 16) & 1u);
  return (u16)(i >> 16);
}
__device__ __forceinline__ float fast_rcp(float x){ return __builtin_amdgcn_rcpf(x); }
__device__ __forceinline__ float sigm(float x){ return fast_rcp(1.0f + __expf(-x)); }
__device__ __forceinline__ float tanh_(float x){ return 1.0f - 2.0f*fast_rcp(__expf(2.0f*x) + 1.0f); }

__device__ __forceinline__ float ld(const void* p, int i, bool isf32){
  return isf32 ? ((const float*)p)[i] : b2f(((const u16*)p)[i]);
}

struct SM {
  float w0[128][128];  // [k][vg]  k<96: W_ih0, k>=96: W_hh0 ; vg = u*4+tt, gate g = tt*32+u
  float w1[64][128];   // [k][vg]  k<32: W_ih1 (x=h0),  k>=32: W_hh1 (h=h1)
  float wm[32][96];    // [k][o]   W_mlp[o][k]
  float xh[128][XS];   // [k][e]   rows 0..95: last/curr pose, 96..127: h0
  float hh[64][XS];    // [k][e]   rows 0..31: h0, 32..63: h1
};

extern "C" __global__ __launch_bounds__(NTHR, 1)
void decoder_kernel(const void* __restrict__ obs,   // [16][B][96]
                    const void* __restrict__ lat,   // [B][16]
                    const void* __restrict__ Wfc,   // [32][16]
                    const void* __restrict__ bfc,   // [32]
                    const void* __restrict__ Wih0,  // [128][96]
                    const void* __restrict__ Whh0,  // [128][32]
                    const void* __restrict__ bih0,  // [128]
                    const void* __restrict__ bhh0,  // [128]
                    const void* __restrict__ Wih1,  // [128][32]
                    const void* __restrict__ Whh1,  // [128][32]
                    const void* __restrict__ bih1,  // [128]
                    const void* __restrict__ bhh1,  // [128]
                    const void* __restrict__ Wmlp,  // [96][32]
                    const void* __restrict__ bmlp,  // [96]
                    void* __restrict__ out)         // [25][B][96]
{
  __shared__ SM sm;
  const int tid = threadIdx.x;
  const int ebase = blockIdx.x * ET;

  // ---- dtype probe (R2-verified): f32 words read as u16 pairs hit big
  //      exponent fields; bf16 N(0,0.01) weights never do. Wave-uniform.
  int cnt = 0;
  {
    const u16* p = (const u16*)Wfc;
    for (int i = 0; i < 512; ++i){
      int e = (p[i] >> 7) & 0xFF;
      cnt += (e >= 0x90);
    }
  }
  const bool isf32 = (cnt > 0);

  // ---- stage weights into LDS (f32), gate-permuted columns ----
  for (int idx = tid; idx < 128*128; idx += NTHR){
    int k = idx >> 7, vg = idx & 127;
    int u = vg >> 2, tt = vg & 3, g = tt*32 + u;
    sm.w0[k][vg] = (k < 96) ? ld(Wih0, g*96 + k, isf32) : ld(Whh0, g*32 + (k-96), isf32);
  }
  for (int idx = tid; idx < 64*128; idx += NTHR){
    int k = idx >> 7, vg = idx & 127;
    int u = vg >> 2, tt = vg & 3, g = tt*32 + u;
    sm.w1[k][vg] = (k < 32) ? ld(Wih1, g*32 + k, isf32) : ld(Whh1, g*32 + (k-32), isf32);
  }
  for (int idx = tid; idx < 32*96; idx += NTHR){
    int k = idx / 96, o = idx - k*96;
    sm.wm[k][o] = ld(Wmlp, o*32 + k, isf32);
  }
  // ---- state init: last = obs_s[15], h0 = h1 = h_init, c = 0 ----
  for (int idx = tid; idx < 96*ET; idx += NTHR){
    int e = idx / 96, p = idx - e*96;
    sm.xh[p][e] = ld(obs, (15*BATCH + ebase + e)*96 + p, isf32);
  }
  for (int idx = tid; idx < 32*ET; idx += NTHR){
    int e = idx >> 5, u = idx & 31;
    float a = ld(bfc, u, isf32);
    const int lbase = (ebase + e)*16;
    #pragma unroll
    for (int j = 0; j < 16; ++j) a = fmaf(ld(Wfc, u*16 + j, isf32), ld(lat, lbase + j, isf32), a);
    sm.xh[96+u][e] = a;
    sm.hh[u][e] = a;
    sm.hh[32+u][e] = a;
  }

  // ---- per-thread tile mapping ----
  const int ug  = tid >> 4;         // unit 0..31
  const int e0  = (tid & 15) * 4;   // 4-elem tile
  const int vg0 = ug * 4;           // this unit's 4 gate-columns (i,f,g,o)
  const int o0  = (tid & 31) * 3;   // MLP: 3 outputs, o-major for coalescing
  const int e0m = (tid >> 5) * 4;   // MLP: 4-elem tile

  float bias0[4], bias1[4];
  #pragma unroll
  for (int tt = 0; tt < 4; ++tt){
    int g = tt*32 + ug;
    bias0[tt] = ld(bih0, g, isf32) + ld(bhh0, g, isf32);
    bias1[tt] = ld(bih1, g, isf32) + ld(bhh1, g, isf32);
  }
  float biasm[3];
  #pragma unroll
  for (int i = 0; i < 3; ++i) biasm[i] = ld(bmlp, o0 + i, isf32);

  float c0s[4], c1s[4];
  #pragma unroll
  for (int j = 0; j < 4; ++j){ c0s[j] = 0.f; c1s[j] = 0.f; }

  __syncthreads();

  for (int t = 0; t < PRED; ++t){
    // ---- GEMM0: gates0 = [last;h0]^T @ w0  (K=128) ----
    float acc[4][4];
    #pragma unroll
    for (int i = 0; i < 4; ++i){
      float b = bias0[i];
      acc[i][0]=b; acc[i][1]=b; acc[i][2]=b; acc[i][3]=b;
    }
    #pragma unroll 4
    for (int k = 0; k < 128; ++k){
      const float4 xv = *(const float4*)&sm.xh[k][e0];
      const float4 wv = *(const float4*)&sm.w0[k][vg0];
      const float xr[4] = {xv.x, xv.y, xv.z, xv.w};
      const float wr[4] = {wv.x, wv.y, wv.z, wv.w};
      #pragma unroll
      for (int i = 0; i < 4; ++i)
        #pragma unroll
        for (int j = 0; j < 4; ++j)
          acc[i][j] = fmaf(wr[i], xr[j], acc[i][j]);
    }
    __syncthreads();   // all xh reads done
    // ---- LSTM0 activation (unit ug x 4 elems, all register-local) ----
    {
      float4 hv;
      float hj[4];
      #pragma unroll
      for (int j = 0; j < 4; ++j){
        float ig = sigm(acc[0][j]);
        float fg = sigm(acc[1][j]);
        float gg = tanh_(acc[2][j]);
        float og = sigm(acc[3][j]);
        float cn = fmaf(fg, c0s[j], ig*gg);
        c0s[j] = cn;
        hj[j] = og * tanh_(cn);
      }
      hv.x = hj[0]; hv.y = hj[1]; hv.z = hj[2]; hv.w = hj[3];
      *(float4*)&sm.xh[96+ug][e0] = hv;
      *(float4*)&sm.hh[ug][e0] = hv;
    }
    __syncthreads();   // h0 visible
    // ---- GEMM1: gates1 = [h0;h1]^T @ w1  (K=64) ----
    #pragma unroll
    for (int i = 0; i < 4; ++i){
      float b = bias1[i];
      acc[i][0]=b; acc[i][1]=b; acc[i][2]=b; acc[i][3]=b;
    }
    #pragma unroll 4
    for (int k = 0; k < 64; ++k){
      const float4 xv = *(const float4*)&sm.hh[k][e0];
      const float4 wv = *(const float4*)&sm.w1[k][vg0];
      const float xr[4] = {xv.x, xv.y, xv.z, xv.w};
      const float wr[4] = {wv.x, wv.y, wv.z, wv.w};
      #pragma unroll
      for (int i = 0; i < 4; ++i)
        #pragma unroll
        for (int j = 0; j < 4; ++j)
          acc[i][j] = fmaf(wr[i], xr[j], acc[i][j]);
    }
    __syncthreads();   // hh reads done
    // ---- LSTM1 activation ----
    {
      float4 hv;
      float hj[4];
      #pragma unroll
      for (int j = 0; j < 4; ++j){
        float ig = sigm(acc[0][j]);
        float fg = sigm(acc[1][j]);
        float gg = tanh_(acc[2][j]);
        float og = sigm(acc[3][j]);
        float cn = fmaf(fg, c1s[j], ig*gg);
        c1s[j] = cn;
        hj[j] = og * tanh_(cn);
      }
      hv.x = hj[0]; hv.y = hj[1]; hv.z = hj[2]; hv.w = hj[3];
      *(float4*)&sm.hh[32+ug][e0] = hv;
    }
    __syncthreads();   // h1 visible
    // ---- MLP: curr = h1^T @ wm + b  (K=32), o-major tile ----
    float am[3][4];
    #pragma unroll
    for (int i = 0; i < 3; ++i){
      float b = biasm[i];
      #pragma unroll
      for (int j = 0; j < 4; ++j) am[i][j] = b;
    }
    #pragma unroll 4
    for (int k = 0; k < 32; ++k){
      const float4 hv = *(const float4*)&sm.hh[32+k][e0m];
      const float hr[4] = {hv.x, hv.y, hv.z, hv.w};
      const float w0r = sm.wm[k][o0];
      const float w1r = sm.wm[k][o0+1];
      const float w2r = sm.wm[k][o0+2];
      #pragma unroll
      for (int j = 0; j < 4; ++j){
        am[0][j] = fmaf(w0r, hr[j], am[0][j]);
        am[1][j] = fmaf(w1r, hr[j], am[1][j]);
        am[2][j] = fmaf(w2r, hr[j], am[2][j]);
      }
    }
    // curr -> xh rows 0..95 (next step's GEMM0 input)
    #pragma unroll
    for (int i = 0; i < 3; ++i)
      #pragma unroll
      for (int j = 0; j < 4; ++j)
        sm.xh[o0+i][e0m+j] = am[i][j];
    // curr -> global, straight from registers (no LDS column read)
    {
      const size_t base = (size_t)t*BATCH*96 + (size_t)(ebase)*96;
      if (isf32){
        float* outf = (float*)out + base + (size_t)e0m*96 + o0;
        #pragma unroll
        for (int j = 0; j < 4; ++j)
          #pragma unroll
          for (int i = 0; i < 3; ++i)
            outf[j*96 + i] = am[i][j];
      } else {
        u16* outh = (u16*)out + base + (size_t)e0m*96 + o0;
        #pragma unroll
        for (int j = 0; j < 4; ++j)
          #pragma unroll
          for (int i = 0; i < 3; ++i)
            outh[j*96 + i] = f2b(am[i][j]);
      }
    }
    __syncthreads();   // curr visible in xh for next step
  }
}

extern "C" void kernel_launch(void* const* d_in, const int* in_sizes, int n_in,
                              void* d_out, int out_size, void* d_ws, size_t ws_size,
                              hipStream_t stream){
  // setup_inputs order; d_in[2] = pred_len (int scalar, ==25 compile-time here)
  decoder_kernel<<<dim3(BATCH/ET), dim3(NTHR), 0, stream>>>(
      d_in[0], d_in[1], d_in[3], d_in[4], d_in[5], d_in[6], d_in[7], d_in[8],
      d_in[9], d_in[10], d_in[11], d_in[12], d_in[13], d_in[14], d_out);
}

// Round 4
// 89.429 us; speedup vs baseline: 6.1549x; 6.1549x over previous
//
#include <hip/hip_runtime.h>

// Decoder: 2-layer LSTM (H=32) + MLP (96), B=16384, 25 steps. MFMA rewrite:
// weights live in VGPRs as 16x16x32 bf16 A-fragments (loaded once); LDS holds
// only bf16 state [e][k] (XOR-swizzled, parity double-buffered h0/h1).
// f32 output via staging buffer. R2 proved inputs/outputs are f32.

#define PRED 25
#define BATCH 16384
#define XROW 192   // xh row (u16): k 0..95 x/curr, 96..127 h0_A, 128..159 h0_B
#define HROW 128   // hh row: k 0..31 h0, 32..63 h1_A, 64..95 h1_B
#define LROW 64    // h1lo row
#define SROW 100   // stage row (f32)

typedef unsigned short u16;
typedef unsigned int   u32;
typedef __attribute__((ext_vector_type(8))) short bf16x8;
typedef __attribute__((ext_vector_type(4))) float f32x4;

__device__ __forceinline__ float fast_rcp(float x){ return __builtin_amdgcn_rcpf(x); }
__device__ __forceinline__ float sigm(float x){ return fast_rcp(1.0f + __expf(-x)); }
__device__ __forceinline__ float tanh_(float x){ return 1.0f - 2.0f*fast_rcp(__expf(2.0f*x) + 1.0f); }
__device__ __forceinline__ u16 f2b(float f){
  u32 i = __float_as_uint(f);
  i += 0x7FFFu + ((i >> 16) & 1u);
  return (u16)(i >> 16);
}
__device__ __forceinline__ float b2f(u16 u){ return __uint_as_float(((u32)u) << 16); }

struct __align__(16) SM {
  u16   xh[64*XROW];
  u16   hh[64*HROW];
  u16   h1lo[64*LROW];
  float stage[64*SROW];
};

__device__ __forceinline__ int swx(int e, int k){ return e*XROW + (k ^ ((e&7)<<3)); }
__device__ __forceinline__ int swh(int e, int k){ return e*HROW + (k ^ ((e&7)<<3)); }
__device__ __forceinline__ int swl(int e, int k){ return e*LROW + (k ^ ((e&7)<<3)); }

__device__ __forceinline__ bf16x8 pack8(float4 f0, float4 f1){
  union { bf16x8 v; u16 u8[8]; } fr;
  fr.u8[0]=f2b(f0.x); fr.u8[1]=f2b(f0.y); fr.u8[2]=f2b(f0.z); fr.u8[3]=f2b(f0.w);
  fr.u8[4]=f2b(f1.x); fr.u8[5]=f2b(f1.y); fr.u8[6]=f2b(f1.z); fr.u8[7]=f2b(f1.w);
  return fr.v;
}

extern "C" __global__ __launch_bounds__(512, 2)
void decoder_kernel(const float* __restrict__ obs,  const float* __restrict__ lat,
                    const float* __restrict__ Wfc,  const float* __restrict__ bfc,
                    const float* __restrict__ Wih0, const float* __restrict__ Whh0,
                    const float* __restrict__ bih0, const float* __restrict__ bhh0,
                    const float* __restrict__ Wih1, const float* __restrict__ Whh1,
                    const float* __restrict__ bih1, const float* __restrict__ bhh1,
                    const float* __restrict__ Wmlp, const float* __restrict__ bmlp,
                    float* __restrict__ out)
{
  __shared__ SM sm;
  const int tid = threadIdx.x;
  const int ebase = blockIdx.x * 64;
  const int w  = tid >> 6;        // wave 0..7
  const int l  = tid & 63;
  const int lr = l & 15;          // row/col within 16-tile
  const int kq = l >> 4;          // k-quad 0..3
  const int nw = w & 3;           // n-tile (e block)
  const int mh = w >> 2;          // m half 0..1
  const int e_ln = nw*16 + lr;    // lane's e column

  // ---- one-time LDS init: x = obs[15], h_init -> h0(parity0), h1(parity0) ----
  {
    int e = tid >> 3, c8 = (tid & 7)*12;
    const float* src = obs + ((size_t)(15*BATCH) + ebase + e)*96 + c8;
    float4 a = *(const float4*)(src);
    float4 b = *(const float4*)(src+4);
    float4 c = *(const float4*)(src+8);
    float v[12] = {a.x,a.y,a.z,a.w,b.x,b.y,b.z,b.w,c.x,c.y,c.z,c.w};
    #pragma unroll
    for (int j = 0; j < 6; ++j){
      u32 pk = (u32)f2b(v[2*j]) | ((u32)f2b(v[2*j+1]) << 16);
      *(u32*)&sm.xh[swx(e, c8 + 2*j)] = pk;
    }
  }
  {
    int u = tid & 31, eb = (tid >> 5)*4;
    const float* wf = Wfc + u*16;
    float bb = bfc[u];
    #pragma unroll
    for (int e4 = 0; e4 < 4; ++e4){
      int e = eb + e4;
      const float* lp = lat + (size_t)(ebase + e)*16;
      float a = bb;
      #pragma unroll
      for (int j = 0; j < 16; ++j) a = fmaf(wf[j], lp[j], a);
      u16 hb = f2b(a);
      sm.xh[swx(e, 96 + u)] = hb;   // h0 parity 0
      sm.hh[swh(e, 32 + u)] = hb;   // h1 parity 0
    }
  }

  // ---- preload weight A-fragments (step-invariant, registers) ----
  // A-frag (16x16x32): lane holds A[row = l&15][k = kq*8 + j], j=0..7
  bf16x8 aw0[4][4];                 // GEMM0: 4 m-tiles x 4 k-chunks
  #pragma unroll
  for (int i = 0; i < 4; ++i){
    int vg = (mh*4 + i)*16 + lr;
    int g  = (vg & 3)*32 + (vg >> 2);   // gate-permuted row
    #pragma unroll
    for (int c = 0; c < 4; ++c){
      int k = c*32 + kq*8;
      const float* src = (k < 96) ? (Wih0 + g*96 + k) : (Whh0 + g*32 + (k - 96));
      aw0[i][c] = pack8(*(const float4*)src, *(const float4*)(src+4));
    }
  }
  bf16x8 aw1[4][2];                 // GEMM1: K=64
  #pragma unroll
  for (int i = 0; i < 4; ++i){
    int vg = (mh*4 + i)*16 + lr;
    int g  = (vg & 3)*32 + (vg >> 2);
    #pragma unroll
    for (int c = 0; c < 2; ++c){
      int k = c*32 + kq*8;
      const float* src = (k < 32) ? (Wih1 + g*32 + k) : (Whh1 + g*32 + (k - 32));
      aw1[i][c] = pack8(*(const float4*)src, *(const float4*)(src+4));
    }
  }
  bf16x8 awm[3];                    // MLP: M=96 -> 3 m-tiles per wave, K=32
  #pragma unroll
  for (int i = 0; i < 3; ++i){
    int o = (mh*3 + i)*16 + lr;
    const float* src = Wmlp + o*32 + kq*8;
    awm[i] = pack8(*(const float4*)src, *(const float4*)(src+4));
  }

  // ---- biases (C-frag layout: row = kq*4 + r) ----
  f32x4 bias0v[4], bias1v[4];
  #pragma unroll
  for (int i = 0; i < 4; ++i){
    int u = (mh*4 + i)*4 + kq;
    #pragma unroll
    for (int r = 0; r < 4; ++r){
      int g = r*32 + u;
      bias0v[i][r] = bih0[g] + bhh0[g];
      bias1v[i][r] = bih1[g] + bhh1[g];
    }
  }
  f32x4 biasmv[3];
  #pragma unroll
  for (int i = 0; i < 3; ++i){
    int o0 = (mh*3 + i)*16 + kq*4;
    #pragma unroll
    for (int r = 0; r < 4; ++r) biasmv[i][r] = bmlp[o0 + r];
  }

  float c0s[4] = {0.f,0.f,0.f,0.f};
  float c1s[4] = {0.f,0.f,0.f,0.f};

  __syncthreads();

  for (int t = 0; t < PRED; ++t){
    const int p = t & 1;
    // ---- P1: GEMM0 gates0[128vg x 64e] = W0 * [x;h0] ----
    bf16x8 bx[4];
    #pragma unroll
    for (int c = 0; c < 3; ++c)
      bx[c] = *(const bf16x8*)&sm.xh[swx(e_ln, c*32 + kq*8)];
    bx[3] = *(const bf16x8*)&sm.xh[swx(e_ln, 96 + 32*p + kq*8)];
    f32x4 g0[4];
    #pragma unroll
    for (int i = 0; i < 4; ++i){
      f32x4 a = bias0v[i];
      #pragma unroll
      for (int c = 0; c < 4; ++c)
        a = __builtin_amdgcn_mfma_f32_16x16x32_bf16(aw0[i][c], bx[c], a, 0, 0, 0);
      g0[i] = a;
    }
    // ---- LSTM0 activation; write h0 to parity p^1 (disjoint from P1 reads) ----
    #pragma unroll
    for (int i = 0; i < 4; ++i){
      float ig = sigm(g0[i][0]);
      float fg = sigm(g0[i][1]);
      float gg = tanh_(g0[i][2]);
      float og = sigm(g0[i][3]);
      float cn = fmaf(fg, c0s[i], ig*gg);
      c0s[i] = cn;
      u16 hb = f2b(og * tanh_(cn));
      int u = (mh*4 + i)*4 + kq;
      sm.xh[swx(e_ln, 96 + 32*(p^1) + u)] = hb;
      sm.hh[swh(e_ln, u)] = hb;
    }
    __syncthreads();   // B2: h0 visible
    // ---- P3: GEMM1 gates1 = W1 * [h0_new; h1_prev] ----
    bf16x8 bh[2];
    bh[0] = *(const bf16x8*)&sm.hh[swh(e_ln, kq*8)];
    bh[1] = *(const bf16x8*)&sm.hh[swh(e_ln, 32 + 32*p + kq*8)];
    f32x4 g1[4];
    #pragma unroll
    for (int i = 0; i < 4; ++i){
      f32x4 a = bias1v[i];
      a = __builtin_amdgcn_mfma_f32_16x16x32_bf16(aw1[i][0], bh[0], a, 0, 0, 0);
      a = __builtin_amdgcn_mfma_f32_16x16x32_bf16(aw1[i][1], bh[1], a, 0, 0, 0);
      g1[i] = a;
    }
    #pragma unroll
    for (int i = 0; i < 4; ++i){
      float ig = sigm(g1[i][0]);
      float fg = sigm(g1[i][1]);
      float gg = tanh_(g1[i][2]);
      float og = sigm(g1[i][3]);
      float cn = fmaf(fg, c1s[i], ig*gg);
      c1s[i] = cn;
      float h1 = og * tanh_(cn);
      u16 hi = f2b(h1);
      u16 lo = f2b(h1 - b2f(hi));
      int u = (mh*4 + i)*4 + kq;
      sm.hh[swh(e_ln, 32 + 32*(p^1) + u)] = hi;   // h1_new (GEMM1 next step + MLP hi)
      sm.h1lo[swl(e_ln, u)] = lo;                 // residual for MLP split
    }
    __syncthreads();   // B4: h1 visible
    // ---- P4: MLP curr[96o x 64e] = Wm * (h1_hi + h1_lo) + b ----
    bf16x8 bmh = *(const bf16x8*)&sm.hh[swh(e_ln, 32 + 32*(p^1) + kq*8)];
    bf16x8 bml = *(const bf16x8*)&sm.h1lo[swl(e_ln, kq*8)];
    #pragma unroll
    for (int i = 0; i < 3; ++i){
      f32x4 a = biasmv[i];
      a = __builtin_amdgcn_mfma_f32_16x16x32_bf16(awm[i], bmh, a, 0, 0, 0);
      a = __builtin_amdgcn_mfma_f32_16x16x32_bf16(awm[i], bml, a, 0, 0, 0);
      int o0 = (mh*3 + i)*16 + kq*4;
      // bf16 feedback into xh rows 0..95 (next step's x)
      u32 pk01 = (u32)f2b(a[0]) | ((u32)f2b(a[1]) << 16);
      u32 pk23 = (u32)f2b(a[2]) | ((u32)f2b(a[3]) << 16);
      *(u32*)&sm.xh[swx(e_ln, o0)]     = pk01;
      *(u32*)&sm.xh[swx(e_ln, o0 + 2)] = pk23;
      // exact f32 -> staging for coalesced output
      *(float2*)&sm.stage[e_ln*SROW + o0]     = make_float2(a[0], a[1]);
      *(float2*)&sm.stage[e_ln*SROW + o0 + 2] = make_float2(a[2], a[3]);
    }
    __syncthreads();   // B5: curr visible (stage + xh)
    // ---- P5: coalesced f32 output ----
    {
      int e = tid >> 3, c8 = (tid & 7)*12;
      float* dst = out + (size_t)t*BATCH*96 + (size_t)(ebase + e)*96 + c8;
      const float* s = &sm.stage[e*SROW + c8];
      float4 v0 = *(const float4*)(s);
      float4 v1 = *(const float4*)(s+4);
      float4 v2 = *(const float4*)(s+8);
      *(float4*)(dst)   = v0;
      *(float4*)(dst+4) = v1;
      *(float4*)(dst+8) = v2;
    }
    // no barrier: next write to stage is P4(t+1), separated by B2/B4(t+1);
    // next write to xh h0 region targets opposite parity; curr region P4(t+1).
  }
}

extern "C" void kernel_launch(void* const* d_in, const int* in_sizes, int n_in,
                              void* d_out, int out_size, void* d_ws, size_t ws_size,
                              hipStream_t stream){
  decoder_kernel<<<dim3(BATCH/64), dim3(512), 0, stream>>>(
      (const float*)d_in[0],  (const float*)d_in[1],
      (const float*)d_in[3],  (const float*)d_in[4],
      (const float*)d_in[5],  (const float*)d_in[6],
      (const float*)d_in[7],  (const float*)d_in[8],
      (const float*)d_in[9],  (const float*)d_in[10],
      (const float*)d_in[11], (const float*)d_in[12],
      (const float*)d_in[13], (const float*)d_in[14],
      (float*)d_out);
}